// Round 10
// baseline (171.941 us; speedup 1.0000x reference)
//
#include <hip/hip_runtime.h>
#include <math.h>

// ---------------------------------------------------------------------------
// MMoE feed-forward, round 9: 2 kernels + 8B memset.
//   memset: zero wsi[608] (xp_done), wsi[609] (conv_done)
//   K1 front: xp (+release count) | wtrans | prep | block 592 = gate
//             (acquire-spin xp_done==512 -> gate + mi_loss + worklist)
//   K2 back : blocks 0..511 conv_fused tiles (+release count)
//             blocks 512..639 combine (acquire-spin conv_done==N)
// Deadlock-free: waits are one-directional (gate<-xp, combine<-conv);
// producers never wait; capacity 4 blocks/CU (39.2KB LDS) >= grid.
// ---------------------------------------------------------------------------

typedef __attribute__((ext_vector_type(8))) short bf16x8;
typedef __attribute__((ext_vector_type(4))) float f32x4;

#define SLOT_ELEMS 524288
#define WT_E       294912            // per expert (both convs)

__device__ inline ushort f2bf(float f) {
  unsigned u = __float_as_uint(f);
  return (ushort)((u + 0x7FFFu + ((u >> 16) & 1u)) >> 16);
}
__device__ inline float bf2f(ushort h) {
  return __uint_as_float(((unsigned)h) << 16);
}
__device__ inline float gelu_fast(float v) {      // tanh-form GELU, err<~4e-4
  float v2 = v * v;
  float z2 = v * fmaf(0.0713548162726f, v2, 1.59576912161f);
  float ex = __expf(-z2);
  return __fdividef(v, 1.0f + ex);
}

// ---------------- K1: xp + wtrans + prep + gate(block 592) ------------------
__global__ __launch_bounds__(256) void front_kernel(const float* __restrict__ x,
                                                    const float* __restrict__ tf,
                                                    const float* __restrict__ Wx,
                                                    const float* __restrict__ Wt,
                                                    const float* __restrict__ cw1,
                                                    const float* __restrict__ cw2,
                                                    float* wsf,
                                                    ushort* __restrict__ wt2,
                                                    ushort* __restrict__ pbuf,
                                                    float* __restrict__ out) {
  int bid = blockIdx.x, tid = threadIdx.x;
  __shared__ union {
    float  red[4];                   // xp reduce
    ushort swT[1152 * 17];           // wtrans transpose: [r=ic*9+tap][oc] 39.2KB
    ushort sT[128 * 65];             // prep transpose
    struct {
      float part[4][64];
      float slog[64], sprob[64], ssum[4];
      int   se[16], snt[8];
    } g;                             // gate
  } sh;
  int* xp_done   = (int*)wsf + 608;

  // ---- A: xp — (b,c) = bid (blocks 0..511) ----
  if (bid < 512) {
    const float4* p = (const float4*)(x + (size_t)bid * 1024);
    float4 v = p[tid];
    float s = v.x + v.y + v.z + v.w;
    #pragma unroll
    for (int off = 32; off > 0; off >>= 1) s += __shfl_down(s, off);
    if ((tid & 63) == 0) sh.red[tid >> 6] = s;
    __syncthreads();
    if (tid == 0) {
      wsf[64 + bid] = (sh.red[0] + sh.red[1] + sh.red[2] + sh.red[3]) *
                      (1.0f / 1024.0f);
      __hip_atomic_fetch_add(xp_done, 1, __ATOMIC_RELEASE,
                             __HIP_MEMORY_SCOPE_AGENT);
    }
    __syncthreads();                 // red dead before sh reuse
  }

  if (bid < 256) {
    // ---- B: wtrans block = (e, which, oc-block) ----
    int e = bid >> 4, which = (bid >> 3) & 1, blk = bid & 7;
    const float* src = (which ? cw2 : cw1) +
                       ((size_t)e * 128 + blk * 16) * 1152;
    #pragma unroll 24
    for (int i = 0; i < 72; ++i) {
      int idx = i * 256 + tid;                 // oc*1152 + r
      int oc = idx / 1152, r = idx - oc * 1152;
      sh.swT[r * 17 + oc] = f2bf(src[idx]);
    }
    __syncthreads();
    // emit MFMA-frag order: 36 chunks, 4 per iter; 16B/lane coalesced stores
    ushort* dst = wt2 + ((size_t)e * 2 + which) * 147456;
    int lane = tid & 63, cq = tid >> 6;
    int ol = lane & 15, h = lane >> 4;
    #pragma unroll
    for (int it = 0; it < 9; ++it) {
      int chunk = it * 4 + cq;                 // tap*4 + icc
      int tap = chunk >> 2, icc = chunk & 3;
      bf16x8 pkv;
      #pragma unroll
      for (int j = 0; j < 8; ++j) {
        int ic = icc * 32 + h * 8 + j;
        pkv[j] = (short)sh.swT[(ic * 9 + tap) * 17 + ol];
      }
      *(bf16x8*)&dst[((size_t)(chunk * 8 + blk)) * 512 + lane * 8] = pkv;
    }
  } else if (bid < 592) {
    // ---- C: prep — chunk pc = bid-256 of 336 (12 variants x 64px chunks) ----
    int pc = bid - 256;
    if (pc < 336) {
      int b = pc / 84, r = pc - (pc / 84) * 84;
      int tp, chunk, S, pp;
      if (r < 16)      { tp = 0; chunk = r;      S = 32; pp = 0; }
      else if (r < 80) { tp = 1; chunk = r - 16; S = 64; pp = 1024; }
      else             { tp = 2; chunk = r - 80; S = 16; pp = 5120; }
      const float* xb = x + (size_t)b * 131072;
      int pxl0 = tid & 63, c0 = tid >> 6;
      #pragma unroll 4
      for (int i = 0; i < 32; ++i) {
        int c = i * 4 + c0;
        int px = chunk * 64 + pxl0;
        float v;
        if (tp == 0) {
          v = xb[c * 1024 + px];
        } else if (tp == 1) {
          int h = px >> 6, w = px & 63;
          v = xb[c * 1024 + (h >> 1) * 32 + (w >> 1)];
        } else {
          int h = px >> 4, w = px & 15;
          const float* p = xb + c * 1024 + (h << 1) * 32 + (w << 1);
          v = fmaxf(fmaxf(p[0], p[1]), fmaxf(p[32], p[33]));
        }
        sh.sT[c * 65 + pxl0] = f2bf(v);
      }
      __syncthreads();
      ushort* ob = pbuf + ((size_t)b * 5376 + pp) * 128;
      #pragma unroll
      for (int i = 0; i < 4; ++i) {
        int u = i * 256 + tid;
        int pxl = u >> 4, q = u & 15;
        bf16x8 pk;
        #pragma unroll
        for (int j = 0; j < 8; ++j) pk[j] = (short)sh.sT[(q * 8 + j) * 65 + pxl];
        *(bf16x8*)&ob[(size_t)(chunk * 64 + pxl) * 128 + q * 8] = pk;
      }
    }
  } else {
    // ---- D: gate (block 592): wait for all 512 xp, then gate+planner ----
    if (tid == 0) {
      while (__hip_atomic_load(xp_done, __ATOMIC_ACQUIRE,
                               __HIP_MEMORY_SCOPE_AGENT) < 512)
        __builtin_amdgcn_s_sleep(2);
    }
    __syncthreads();

    int p = tid >> 6, be = tid & 63;
    int b = be >> 4, e = be & 15;
    const float* xp = wsf + 64;

    float acc = 0.0f;
    #pragma unroll 8
    for (int c = p * 32; c < p * 32 + 32; ++c)
      acc += xp[b * 128 + c] * Wx[c * 16 + e];
    {
      const float4* tf4 = (const float4*)(tf + b * 512 + p * 128);
      #pragma unroll 8
      for (int d4 = 0; d4 < 32; ++d4) {
        float4 t4 = tf4[d4];
        int d = p * 128 + d4 * 4;
        acc += t4.x * Wt[(d + 0) * 16 + e];
        acc += t4.y * Wt[(d + 1) * 16 + e];
        acc += t4.z * Wt[(d + 2) * 16 + e];
        acc += t4.w * Wt[(d + 3) * 16 + e];
      }
    }
    sh.g.part[p][be] = acc;
    __syncthreads();

    if (tid < 64) sh.g.slog[be] = sh.g.part[0][be] + sh.g.part[1][be] +
                                  sh.g.part[2][be] + sh.g.part[3][be];
    __syncthreads();
    if (tid < 64) {
      float m = sh.g.slog[b * 16];
      for (int j = 1; j < 16; ++j) m = fmaxf(m, sh.g.slog[b * 16 + j]);
      sh.g.sprob[be] = expf(sh.g.slog[be] - m);
    }
    __syncthreads();
    if (tid < 4) {                            // tid = b
      float s = 0.0f;
      for (int j = 0; j < 16; ++j) s += sh.g.sprob[tid * 16 + j];
      sh.g.ssum[tid] = s;
      int i1 = 0; float v1 = -1.0f;
      for (int j = 0; j < 16; ++j) {
        float v = sh.g.sprob[tid * 16 + j];
        if (v > v1) { v1 = v; i1 = j; }
      }
      int i2 = -1; float v2 = -1.0f;
      for (int j = 0; j < 16; ++j) {
        if (j == i1) continue;
        float v = sh.g.sprob[tid * 16 + j];
        if (v > v2) { v2 = v; i2 = j; }
      }
      float inv = 1.0f / (v1 + v2);           // softmax denom cancels
      int* wsi = (int*)wsf;
      wsi[2 * tid]     = i1;  wsi[2 * tid + 1]     = i2;
      wsi[8 + 2 * tid] = tid; wsi[8 + 2 * tid + 1] = tid;
      wsf[16 + 2 * tid]     = v1 * inv;
      wsf[16 + 2 * tid + 1] = v2 * inv;
      sh.g.se[2 * tid] = i1; sh.g.se[2 * tid + 1] = i2;
    }
    __syncthreads();
    if (tid < 8) {
      int ee = sh.g.se[tid];
      int tp = ee % 3;
      sh.g.snt[tid] = (tp == 0) ? 16 : ((tp == 1) ? 64 : 4);
    }
    __syncthreads();
    if (tid < 8) {                            // parallel planner: stores only
      int pre = 0;
      #pragma unroll
      for (int s = 0; s < 8; ++s) pre += (s < tid) ? sh.g.snt[s] : 0;
      int ee = sh.g.se[tid];
      int tp = ee % 3;
      int nt = sh.g.snt[tid];
      int bb = tid >> 1;
      int ent_base = tid | (ee << 12) | (tp << 16) | (bb << 20);
      int* wl = (int*)wsf + 640;
      for (int t = 0; t < nt; ++t) wl[pre + t] = ent_base | (t << 4);
      if (tid == 7) ((int*)wsf)[600] = pre + nt;
    }
    if (tid == 32) {
      float kl = 0.0f;
      for (int j = 0; j < 16; ++j) {
        float pe = 0.25f * (sh.g.sprob[j] / sh.g.ssum[0] +
                            sh.g.sprob[16 + j] / sh.g.ssum[1] +
                            sh.g.sprob[32 + j] / sh.g.ssum[2] +
                            sh.g.sprob[48 + j] / sh.g.ssum[3]);
        kl += pe * logf(pe / (pe + 1e-7f) + 1e-7f);
      }
      out[524288] = -0.01f * kl;              // mi_loss
    }
  }
}

// ---------------- K2: conv tiles (0..511) + combine (512..639) --------------
__global__ __launch_bounds__(256, 2) void back_kernel(float* wsf,
                                                      const ushort* __restrict__ pbuf,
                                                      ushort* __restrict__ buf0,
                                                      const ushort* __restrict__ wt2,
                                                      const float* __restrict__ cb1,
                                                      const float* __restrict__ cb2,
                                                      float* __restrict__ out) {
  const int* wsi = (const int*)wsf;
  int* conv_done = (int*)wsf + 609;
  int bid = blockIdx.x, tid = threadIdx.x;
  __shared__ union {
    ushort sLDS[144 * 136];          // conv: 12x12 halo then 10x10 mid (39.2KB)
    float  sO[32 * 129];             // combine transpose
  } sh;

  if (bid < 512) {
    // ======================= conv phase =======================
    if (bid >= wsi[600]) return;
    int ent = wsi[640 + bid];
    int slot = ent & 7;
    int tile = (ent >> 4) & 63;
    int e    = (ent >> 12) & 15;
    int tp   = (ent >> 16) & 3;
    int b    = (ent >> 20) & 3;
    int S = (tp == 0) ? 32 : ((tp == 1) ? 64 : 16);
    int tpr = S >> 3;
    int tr = (tile / tpr) << 3;
    int tc = (tile % tpr) << 3;

    const ushort* in =
        pbuf + ((size_t)b * 5376 + (tp == 0 ? 0 : (tp == 1 ? 1024 : 5120))) * 128;
    ushort* outp = buf0 + (size_t)slot * SLOT_ELEMS;

    // ---- stage 12x12 input halo (from tr-2, tc-2), zero-padded ----
    for (int u = tid; u < 2304; u += 256) {
      int p = u >> 4, q = u & 15;
      int hr = p / 12, wc = p - hr * 12;
      int gh = tr + hr - 2, gw = tc + wc - 2;
      bf16x8 v = {0, 0, 0, 0, 0, 0, 0, 0};
      if (gh >= 0 && gh < S && gw >= 0 && gw < S)
        v = *(const bf16x8*)&in[(size_t)(gh * S + gw) * 128 + q * 8];
      *(bf16x8*)&sh.sLDS[p * 136 + q * 8] = v;
    }

    int wid = tid >> 6, lane = tid & 63;
    int ln = lane & 15, lg = lane >> 4;
    int ocw = wid << 5;
    const float* bias1 = cb1 + e * 128;
    const float* bias2 = cb2 + e * 128;

    const ushort* wbase1 = wt2 + ((size_t)e * 2 + 0) * 147456
                           + (size_t)(wid * 2) * 512 + lane * 8;
    const ushort* wbase2 = wt2 + ((size_t)e * 2 + 1) * 147456
                           + (size_t)(wid * 2) * 512 + lane * 8;

    float bv1[2][4];
    #pragma unroll
    for (int m = 0; m < 2; ++m)
      #pragma unroll
      for (int j = 0; j < 4; ++j) bv1[m][j] = bias1[ocw + m * 16 + lg * 4 + j];

    bf16x8 abuf[3][2];
    #pragma unroll
    for (int i = 0; i < 2; ++i) {
      abuf[i][0] = *(const bf16x8*)&wbase1[(size_t)i * 4096];
      abuf[i][1] = *(const bf16x8*)&wbase1[(size_t)i * 4096 + 512];
    }

    __syncthreads();                          // staging complete

    // ======== conv1 pass A: frags 0..3, px 0..63 (all valid) ========
    uint2 pkA[2][4];
    {
      f32x4 acc[2][4];
      #pragma unroll
      for (int m = 0; m < 2; ++m)
        #pragma unroll
        for (int n = 0; n < 4; ++n)
          #pragma unroll
          for (int j = 0; j < 4; ++j) acc[m][n][j] = bv1[m][j];
      int pxb[4], r1a[4], c1a[4];
      #pragma unroll
      for (int n = 0; n < 4; ++n) {
        int px = n * 16 + ln;                 // 0..63
        int r1 = px / 10, c1 = px - r1 * 10;
        r1a[n] = r1; c1a[n] = c1;
        pxb[n] = r1 * 12 + c1;
      }
      #pragma unroll 6
      for (int kk = 0; kk < 36; ++kk) {
        if (kk + 2 < 36) {
          abuf[(kk + 2) % 3][0] = *(const bf16x8*)&wbase1[(size_t)(kk + 2) * 4096];
          abuf[(kk + 2) % 3][1] = *(const bf16x8*)&wbase1[(size_t)(kk + 2) * 4096 + 512];
        }
        int tap = kk >> 2, icc = kk & 3;
        int off = (tap / 3) * 12 + (tap % 3);
        bf16x8 bfr[4];
        #pragma unroll
        for (int n = 0; n < 4; ++n)
          bfr[n] = *(bf16x8*)&sh.sLDS[(pxb[n] + off) * 136 + icc * 32 + lg * 8];
        #pragma unroll
        for (int m = 0; m < 2; ++m)
          #pragma unroll
          for (int n = 0; n < 4; ++n)
            acc[m][n] = __builtin_amdgcn_mfma_f32_16x16x32_bf16(abuf[kk % 3][m], bfr[n],
                                                                acc[m][n], 0, 0, 0);
      }
      #pragma unroll
      for (int m = 0; m < 2; ++m)
        #pragma unroll
        for (int n = 0; n < 4; ++n) {
          int g1 = tr - 1 + r1a[n], w1 = tc - 1 + c1a[n];
          bool valid = (g1 >= 0) && (g1 < S) && (w1 >= 0) && (w1 < S);
          uint2 st;
          if (valid) {
            st.x = (unsigned)f2bf(gelu_fast(acc[m][n][0])) |
                   ((unsigned)f2bf(gelu_fast(acc[m][n][1])) << 16);
            st.y = (unsigned)f2bf(gelu_fast(acc[m][n][2])) |
                   ((unsigned)f2bf(gelu_fast(acc[m][n][3])) << 16);
          } else { st.x = 0; st.y = 0; }
          pkA[m][n] = st;
        }
    }

    // ======== conv1 pass B: frags 4..6, px 64..111 (valid < 100) ========
    uint2 pkB[2][3];
    {
      #pragma unroll
      for (int i = 0; i < 2; ++i) {
        abuf[i][0] = *(const bf16x8*)&wbase1[(size_t)i * 4096];
        abuf[i][1] = *(const bf16x8*)&wbase1[(size_t)i * 4096 + 512];
      }
      f32x4 acc[2][3];
      #pragma unroll
      for (int m = 0; m < 2; ++m)
        #pragma unroll
        for (int n = 0; n < 3; ++n)
          #pragma unroll
          for (int j = 0; j < 4; ++j) acc[m][n][j] = bv1[m][j];
      int pxb[3], r1a[3], c1a[3];
      #pragma unroll
      for (int n = 0; n < 3; ++n) {
        int px = 64 + n * 16 + ln;            // 64..111
        int r1 = px / 10, c1 = px - r1 * 10;
        r1a[n] = r1; c1a[n] = c1;
        pxb[n] = (px < 100) ? (r1 * 12 + c1) : 0;
      }
      #pragma unroll 6
      for (int kk = 0; kk < 36; ++kk) {
        if (kk + 2 < 36) {
          abuf[(kk + 2) % 3][0] = *(const bf16x8*)&wbase1[(size_t)(kk + 2) * 4096];
          abuf[(kk + 2) % 3][1] = *(const bf16x8*)&wbase1[(size_t)(kk + 2) * 4096 + 512];
        }
        int tap = kk >> 2, icc = kk & 3;
        int off = (tap / 3) * 12 + (tap % 3);
        bf16x8 bfr[3];
        #pragma unroll
        for (int n = 0; n < 3; ++n)
          bfr[n] = *(bf16x8*)&sh.sLDS[(pxb[n] + off) * 136 + icc * 32 + lg * 8];
        #pragma unroll
        for (int m = 0; m < 2; ++m)
          #pragma unroll
          for (int n = 0; n < 3; ++n)
            acc[m][n] = __builtin_amdgcn_mfma_f32_16x16x32_bf16(abuf[kk % 3][m], bfr[n],
                                                                acc[m][n], 0, 0, 0);
      }
      #pragma unroll
      for (int m = 0; m < 2; ++m)
        #pragma unroll
        for (int n = 0; n < 3; ++n) {
          int g1 = tr - 1 + r1a[n], w1 = tc - 1 + c1a[n];
          bool valid = (g1 >= 0) && (g1 < S) && (w1 >= 0) && (w1 < S);
          uint2 st;
          if (valid) {
            st.x = (unsigned)f2bf(gelu_fast(acc[m][n][0])) |
                   ((unsigned)f2bf(gelu_fast(acc[m][n][1])) << 16);
            st.y = (unsigned)f2bf(gelu_fast(acc[m][n][2])) |
                   ((unsigned)f2bf(gelu_fast(acc[m][n][3])) << 16);
          } else { st.x = 0; st.y = 0; }
          pkB[m][n] = st;
        }
    }

    // prefetch conv2's first A-frags
    #pragma unroll
    for (int i = 0; i < 2; ++i) {
      abuf[i][0] = *(const bf16x8*)&wbase2[(size_t)i * 4096];
      abuf[i][1] = *(const bf16x8*)&wbase2[(size_t)i * 4096 + 512];
    }

    __syncthreads();                          // all conv1 LDS reads done

    // ---- write mid 10x10 tile into sLDS rows 0..99 ----
    #pragma unroll
    for (int m = 0; m < 2; ++m) {
      int oc0 = ocw + m * 16 + lg * 4;
      #pragma unroll
      for (int n = 0; n < 4; ++n) {
        int px = n * 16 + ln;
        *(uint2*)&sh.sLDS[px * 136 + oc0] = pkA[m][n];
      }
      #pragma unroll
      for (int n = 0; n < 3; ++n) {
        int px = 64 + n * 16 + ln;
        if (px < 100) *(uint2*)&sh.sLDS[px * 136 + oc0] = pkB[m][n];
      }
    }
    __syncthreads();                          // sMid ready

    // ======== conv2: 36 x (2m x 4n) MFMA ========
    f32x4 acc2[2][4];
    #pragma unroll
    for (int m = 0; m < 2; ++m) {
      #pragma unroll
      for (int j = 0; j < 4; ++j) {
        float bv = bias2[ocw + m * 16 + lg * 4 + j];
        #pragma unroll
        for (int n = 0; n < 4; ++n) acc2[m][n][j] = bv;
      }
    }
    int pxb2[4];
    #pragma unroll
    for (int n = 0; n < 4; ++n) {
      int px = n * 16 + ln;
      pxb2[n] = (px >> 3) * 10 + (px & 7);
    }

    bf16x8 bcur[4], bnxt[4];
    #pragma unroll
    for (int n = 0; n < 4; ++n)               // k=0: tap 0, icc 0
      bcur[n] = *(bf16x8*)&sh.sLDS[pxb2[n] * 136 + lg * 8];

    #pragma unroll 6
    for (int kk = 0; kk < 36; ++kk) {
      if (kk + 2 < 36) {
        abuf[(kk + 2) % 3][0] = *(const bf16x8*)&wbase2[(size_t)(kk + 2) * 4096];
        abuf[(kk + 2) % 3][1] = *(const bf16x8*)&wbase2[(size_t)(kk + 2) * 4096 + 512];
      }
      int kn = kk + 1;
      if (kn < 36) {
        int tapn = kn >> 2, iccn = kn & 3;
        int offn = (tapn / 3) * 10 + (tapn % 3);
        #pragma unroll
        for (int n = 0; n < 4; ++n)
          bnxt[n] = *(bf16x8*)&sh.sLDS[(pxb2[n] + offn) * 136 + iccn * 32 + lg * 8];
      }
      #pragma unroll
      for (int m = 0; m < 2; ++m)
        #pragma unroll
        for (int n = 0; n < 4; ++n)
          acc2[m][n] = __builtin_amdgcn_mfma_f32_16x16x32_bf16(abuf[kk % 3][m], bcur[n],
                                                               acc2[m][n], 0, 0, 0);
      #pragma unroll
      for (int n = 0; n < 4; ++n) bcur[n] = bnxt[n];
    }

    // ---- epilogue: pack bf16, NHWC store ----
    #pragma unroll
    for (int m = 0; m < 2; ++m) {
      int oc0 = ocw + m * 16 + lg * 4;
      #pragma unroll
      for (int n = 0; n < 4; ++n) {
        int px = n * 16 + ln;
        int gh = tr + (px >> 3), gw = tc + (px & 7);
        unsigned pk0 = (unsigned)f2bf(acc2[m][n][0]) | ((unsigned)f2bf(acc2[m][n][1]) << 16);
        unsigned pk1 = (unsigned)f2bf(acc2[m][n][2]) | ((unsigned)f2bf(acc2[m][n][3]) << 16);
        uint2 st; st.x = pk0; st.y = pk1;
        *(uint2*)&outp[(size_t)(gh * S + gw) * 128 + oc0] = st;
      }
    }

    // ---- signal: stores are vmcnt-drained by syncthreads; release covers
    //      the block's writes via this XCD's L2 writeback ----
    __syncthreads();
    if (tid == 0)
      __hip_atomic_fetch_add(conv_done, 1, __ATOMIC_RELEASE,
                             __HIP_MEMORY_SCOPE_AGENT);
  } else {
    // ======================= combine phase =======================
    int cb = bid - 512;                       // 0..127
    int chunk = cb & 31, b = cb >> 5;
    int N = wsi[600];
    if (tid == 0) {
      while (__hip_atomic_load(conv_done, __ATOMIC_ACQUIRE,
                               __HIP_MEMORY_SCOPE_AGENT) < N)
        __builtin_amdgcn_s_sleep(2);
    }
    __syncthreads();

    #pragma unroll
    for (int i = 0; i < 2; ++i) {
      int u = i * 256 + tid;
      int pxl = u >> 4, q = u & 15;
      int px = chunk * 32 + pxl;
      int h = px >> 5, w = px & 31;
      float a8[8];
      #pragma unroll
      for (int j = 0; j < 8; ++j) a8[j] = 0.0f;

      for (int s = 0; s < 2; ++s) {
        int slot = 2 * b + s;
        int e = wsi[slot];
        float g = wsf[16 + slot];
        int tp = e % 3;
        const ushort* cin = buf0 + (size_t)slot * SLOT_ELEMS;
        if (tp == 0) {
          bf16x8 v = *(const bf16x8*)&cin[(size_t)(h * 32 + w) * 128 + q * 8];
          #pragma unroll
          for (int j = 0; j < 8; ++j) a8[j] += g * bf2f((ushort)v[j]);
        } else if (tp == 1) {                 // maxpool from 64x64
          bf16x8 v00 = *(const bf16x8*)&cin[(size_t)((2*h) * 64 + 2*w) * 128 + q * 8];
          bf16x8 v01 = *(const bf16x8*)&cin[(size_t)((2*h) * 64 + 2*w + 1) * 128 + q * 8];
          bf16x8 v10 = *(const bf16x8*)&cin[(size_t)((2*h+1) * 64 + 2*w) * 128 + q * 8];
          bf16x8 v11 = *(const bf16x8*)&cin[(size_t)((2*h+1) * 64 + 2*w + 1) * 128 + q * 8];
          #pragma unroll
          for (int j = 0; j < 8; ++j) {
            float mv = fmaxf(fmaxf(bf2f((ushort)v00[j]), bf2f((ushort)v01[j])),
                             fmaxf(bf2f((ushort)v10[j]), bf2f((ushort)v11[j])));
            a8[j] += g * mv;
          }
        } else {                              // bilinear up from 16x16
          float sh2 = h * 0.5f - 0.25f, sw2 = w * 0.5f - 0.25f;
          float fh0 = floorf(sh2), fw0 = floorf(sw2);
          int h0 = (int)fh0, w0 = (int)fw0;
          float fh = sh2 - fh0, fw = sw2 - fw0;
          int h0c = h0 < 0 ? 0 : h0, h1c = (h0 + 1 > 15) ? 15 : h0 + 1;
          int w0c = w0 < 0 ? 0 : w0, w1c = (w0 + 1 > 15) ? 15 : w0 + 1;
          bf16x8 v00 = *(const bf16x8*)&cin[(size_t)(h0c * 16 + w0c) * 128 + q * 8];
          bf16x8 v01 = *(const bf16x8*)&cin[(size_t)(h0c * 16 + w1c) * 128 + q * 8];
          bf16x8 v10 = *(const bf16x8*)&cin[(size_t)(h1c * 16 + w0c) * 128 + q * 8];
          bf16x8 v11 = *(const bf16x8*)&cin[(size_t)(h1c * 16 + w1c) * 128 + q * 8];
          #pragma unroll
          for (int j = 0; j < 8; ++j) {
            float vv = (1.0f - fh) * ((1.0f - fw) * bf2f((ushort)v00[j]) + fw * bf2f((ushort)v01[j])) +
                       fh * ((1.0f - fw) * bf2f((ushort)v10[j]) + fw * bf2f((ushort)v11[j]));
            a8[j] += g * vv;
          }
        }
      }
      #pragma unroll
      for (int j = 0; j < 8; ++j) sh.sO[pxl * 129 + q * 8 + j] = a8[j];
    }
    __syncthreads();
    float* ob = out + (size_t)b * 131072;
    #pragma unroll 4
    for (int i = 0; i < 16; ++i) {
      int u = i * 256 + tid;
      int c = u >> 5, pxl = u & 31;
      ob[(size_t)c * 1024 + chunk * 32 + pxl] = sh.sO[pxl * 129 + c];
    }
  }
}

// ---------------------------------------------------------------------------
extern "C" void kernel_launch(void* const* d_in, const int* in_sizes, int n_in,
                              void* d_out, int out_size, void* d_ws, size_t ws_size,
                              hipStream_t stream) {
  const float* x   = (const float*)d_in[0];
  const float* tf  = (const float*)d_in[1];
  const float* Wx  = (const float*)d_in[2];
  const float* Wt  = (const float*)d_in[3];
  const float* cw1 = (const float*)d_in[4];
  const float* cb1 = (const float*)d_in[5];
  const float* cw2 = (const float*)d_in[6];
  const float* cb2 = (const float*)d_in[7];
  float* out = (float*)d_out;

  float*  wsf  = (float*)d_ws;                    // 4096 f32
  ushort* wt2  = (ushort*)(wsf + 4096);           // 16*294912
  ushort* pbuf = wt2 + 16 * (size_t)WT_E;         // 4*5376*128
  ushort* buf0 = pbuf + 4 * 5376 * 128;           // 8*524288

  // zero xp_done / conv_done counters (ws is poisoned 0xAA before timing)
  hipMemsetAsync((char*)d_ws + 608 * sizeof(int), 0, 2 * sizeof(int), stream);

  hipLaunchKernelGGL(front_kernel, dim3(593), dim3(256), 0, stream,
                     x, tf, Wx, Wt, cw1, cw2, wsf, wt2, pbuf, out);
  hipLaunchKernelGGL(back_kernel,  dim3(640), dim3(256), 0, stream,
                     wsf, pbuf, buf0, wt2, cb1, cb2, out);
}

// Round 11
// 69.263 us; speedup vs baseline: 2.4824x; 2.4824x over previous
//
#include <hip/hip_runtime.h>
#include <math.h>

// ---------------------------------------------------------------------------
// MMoE feed-forward, round 10: round-6 split-conv structure (best measured)
// + gate folded into front via RELAXED spin + one acquire fence (r9 lesson:
// acquire-in-loop at agent scope invalidates the XCD L2 per poll).
//   memset: zero wsi[608] (xp_done)
//   K1 frontG: xp(+release cnt) | wtrans | prep | block 592 = gate
//   K2 conv1 : worklist implicit-GEMM (bias + fast GELU)
//   K3 conv2 : worklist implicit-GEMM (bias)
//   K4 combine: post-transform * gate -> NCHW f32
// ---------------------------------------------------------------------------

typedef __attribute__((ext_vector_type(8))) short bf16x8;
typedef __attribute__((ext_vector_type(4))) float f32x4;

#define SLOT_ELEMS 524288
#define WT_E       294912            // per expert (both convs)

__device__ inline ushort f2bf(float f) {
  unsigned u = __float_as_uint(f);
  return (ushort)((u + 0x7FFFu + ((u >> 16) & 1u)) >> 16);
}
__device__ inline float bf2f(ushort h) {
  return __uint_as_float(((unsigned)h) << 16);
}
__device__ inline float gelu_fast(float v) {      // tanh-form GELU, err<~4e-4
  float v2 = v * v;
  float z2 = v * fmaf(0.0713548162726f, v2, 1.59576912161f);
  float ex = __expf(-z2);
  return __fdividef(v, 1.0f + ex);
}

// ---------------- K1: xp + wtrans + prep + gate(block 592) ------------------
__global__ __launch_bounds__(256) void front_kernel(const float* __restrict__ x,
                                                    const float* __restrict__ tf,
                                                    const float* __restrict__ Wx,
                                                    const float* __restrict__ Wt,
                                                    const float* __restrict__ cw1,
                                                    const float* __restrict__ cw2,
                                                    float* wsf,
                                                    ushort* __restrict__ wt2,
                                                    ushort* __restrict__ pbuf,
                                                    float* __restrict__ out) {
  int bid = blockIdx.x, tid = threadIdx.x;
  __shared__ union {
    float  red[4];                   // xp reduce
    ushort swT[1152 * 17];           // wtrans transpose: [r=ic*9+tap][oc] 39.2KB
    ushort sT[128 * 65];             // prep transpose
    struct {
      float part[4][64];
      float slog[64], sprob[64], ssum[4];
      int   se[16], snt[8];
    } g;                             // gate
  } sh;
  int* xp_done = (int*)wsf + 608;

  // ---- A: xp — (b,c) = bid (blocks 0..511) ----
  if (bid < 512) {
    const float4* p = (const float4*)(x + (size_t)bid * 1024);
    float4 v = p[tid];
    float s = v.x + v.y + v.z + v.w;
    #pragma unroll
    for (int off = 32; off > 0; off >>= 1) s += __shfl_down(s, off);
    if ((tid & 63) == 0) sh.red[tid >> 6] = s;
    __syncthreads();
    if (tid == 0) {
      wsf[64 + bid] = (sh.red[0] + sh.red[1] + sh.red[2] + sh.red[3]) *
                      (1.0f / 1024.0f);
      __hip_atomic_fetch_add(xp_done, 1, __ATOMIC_RELEASE,
                             __HIP_MEMORY_SCOPE_AGENT);
    }
    __syncthreads();                 // red dead before sh reuse
  }

  if (bid < 256) {
    // ---- B: wtrans block = (e, which, oc-block) ----
    int e = bid >> 4, which = (bid >> 3) & 1, blk = bid & 7;
    const float* src = (which ? cw2 : cw1) +
                       ((size_t)e * 128 + blk * 16) * 1152;
    #pragma unroll 24
    for (int i = 0; i < 72; ++i) {
      int idx = i * 256 + tid;                 // oc*1152 + r
      int oc = idx / 1152, r = idx - oc * 1152;
      sh.swT[r * 17 + oc] = f2bf(src[idx]);
    }
    __syncthreads();
    // emit MFMA-frag order: 36 chunks, 4 per iter; 16B/lane coalesced stores
    ushort* dst = wt2 + ((size_t)e * 2 + which) * 147456;
    int lane = tid & 63, cq = tid >> 6;
    int ol = lane & 15, h = lane >> 4;
    #pragma unroll
    for (int it = 0; it < 9; ++it) {
      int chunk = it * 4 + cq;                 // tap*4 + icc
      int tap = chunk >> 2, icc = chunk & 3;
      bf16x8 pkv;
      #pragma unroll
      for (int j = 0; j < 8; ++j) {
        int ic = icc * 32 + h * 8 + j;
        pkv[j] = (short)sh.swT[(ic * 9 + tap) * 17 + ol];
      }
      *(bf16x8*)&dst[((size_t)(chunk * 8 + blk)) * 512 + lane * 8] = pkv;
    }
  } else if (bid < 592) {
    // ---- C: prep — chunk pc = bid-256 of 336 (12 variants x 64px chunks) ----
    int pc = bid - 256;
    if (pc < 336) {
      int b = pc / 84, r = pc - (pc / 84) * 84;
      int tp, chunk, S, pp;
      if (r < 16)      { tp = 0; chunk = r;      S = 32; pp = 0; }
      else if (r < 80) { tp = 1; chunk = r - 16; S = 64; pp = 1024; }
      else             { tp = 2; chunk = r - 80; S = 16; pp = 5120; }
      const float* xb = x + (size_t)b * 131072;
      int pxl0 = tid & 63, c0 = tid >> 6;
      #pragma unroll 4
      for (int i = 0; i < 32; ++i) {
        int c = i * 4 + c0;
        int px = chunk * 64 + pxl0;
        float v;
        if (tp == 0) {
          v = xb[c * 1024 + px];
        } else if (tp == 1) {
          int h = px >> 6, w = px & 63;
          v = xb[c * 1024 + (h >> 1) * 32 + (w >> 1)];
        } else {
          int h = px >> 4, w = px & 15;
          const float* p = xb + c * 1024 + (h << 1) * 32 + (w << 1);
          v = fmaxf(fmaxf(p[0], p[1]), fmaxf(p[32], p[33]));
        }
        sh.sT[c * 65 + pxl0] = f2bf(v);
      }
      __syncthreads();
      ushort* ob = pbuf + ((size_t)b * 5376 + pp) * 128;
      #pragma unroll
      for (int i = 0; i < 4; ++i) {
        int u = i * 256 + tid;
        int pxl = u >> 4, q = u & 15;
        bf16x8 pk;
        #pragma unroll
        for (int j = 0; j < 8; ++j) pk[j] = (short)sh.sT[(q * 8 + j) * 65 + pxl];
        *(bf16x8*)&ob[(size_t)(chunk * 64 + pxl) * 128 + q * 8] = pk;
      }
    }
  } else {
    // ---- D: gate (block 592): RELAXED spin for 512 xp, one acquire fence ----
    if (tid == 0) {
      while (__hip_atomic_load(xp_done, __ATOMIC_RELAXED,
                               __HIP_MEMORY_SCOPE_AGENT) < 512)
        __builtin_amdgcn_s_sleep(2);
      __builtin_amdgcn_fence(__ATOMIC_ACQUIRE, "agent");
    }
    __syncthreads();

    int p = tid >> 6, be = tid & 63;
    int b = be >> 4, e = be & 15;
    const float* xp = wsf + 64;

    float acc = 0.0f;
    #pragma unroll 8
    for (int c = p * 32; c < p * 32 + 32; ++c)
      acc += xp[b * 128 + c] * Wx[c * 16 + e];
    {
      const float4* tf4 = (const float4*)(tf + b * 512 + p * 128);
      #pragma unroll 8
      for (int d4 = 0; d4 < 32; ++d4) {
        float4 t4 = tf4[d4];
        int d = p * 128 + d4 * 4;
        acc += t4.x * Wt[(d + 0) * 16 + e];
        acc += t4.y * Wt[(d + 1) * 16 + e];
        acc += t4.z * Wt[(d + 2) * 16 + e];
        acc += t4.w * Wt[(d + 3) * 16 + e];
      }
    }
    sh.g.part[p][be] = acc;
    __syncthreads();

    if (tid < 64) sh.g.slog[be] = sh.g.part[0][be] + sh.g.part[1][be] +
                                  sh.g.part[2][be] + sh.g.part[3][be];
    __syncthreads();
    if (tid < 64) {
      float m = sh.g.slog[b * 16];
      for (int j = 1; j < 16; ++j) m = fmaxf(m, sh.g.slog[b * 16 + j]);
      sh.g.sprob[be] = expf(sh.g.slog[be] - m);
    }
    __syncthreads();
    if (tid < 4) {                            // tid = b
      float s = 0.0f;
      for (int j = 0; j < 16; ++j) s += sh.g.sprob[tid * 16 + j];
      sh.g.ssum[tid] = s;
      int i1 = 0; float v1 = -1.0f;
      for (int j = 0; j < 16; ++j) {
        float v = sh.g.sprob[tid * 16 + j];
        if (v > v1) { v1 = v; i1 = j; }
      }
      int i2 = -1; float v2 = -1.0f;
      for (int j = 0; j < 16; ++j) {
        if (j == i1) continue;
        float v = sh.g.sprob[tid * 16 + j];
        if (v > v2) { v2 = v; i2 = j; }
      }
      float inv = 1.0f / (v1 + v2);           // softmax denom cancels
      int* wsi = (int*)wsf;
      wsi[2 * tid]     = i1;  wsi[2 * tid + 1]     = i2;
      wsi[8 + 2 * tid] = tid; wsi[8 + 2 * tid + 1] = tid;
      wsf[16 + 2 * tid]     = v1 * inv;
      wsf[16 + 2 * tid + 1] = v2 * inv;
      sh.g.se[2 * tid] = i1; sh.g.se[2 * tid + 1] = i2;
    }
    __syncthreads();
    if (tid < 8) {
      int ee = sh.g.se[tid];
      int tp = ee % 3;
      sh.g.snt[tid] = (tp == 0) ? 16 : ((tp == 1) ? 64 : 4);
    }
    __syncthreads();
    if (tid < 8) {                            // parallel planner: stores only
      int pre = 0;
      #pragma unroll
      for (int s = 0; s < 8; ++s) pre += (s < tid) ? sh.g.snt[s] : 0;
      int ee = sh.g.se[tid];
      int tp = ee % 3;
      int nt = sh.g.snt[tid];
      int bb = tid >> 1;
      int ent_base = tid | (ee << 12) | (tp << 16) | (bb << 20);
      int* wl = (int*)wsf + 640;
      for (int t = 0; t < nt; ++t) wl[pre + t] = ent_base | (t << 4);
      if (tid == 7) ((int*)wsf)[600] = pre + nt;
    }
    if (tid == 32) {
      float kl = 0.0f;
      for (int j = 0; j < 16; ++j) {
        float pe = 0.25f * (sh.g.sprob[j] / sh.g.ssum[0] +
                            sh.g.sprob[16 + j] / sh.g.ssum[1] +
                            sh.g.sprob[32 + j] / sh.g.ssum[2] +
                            sh.g.sprob[48 + j] / sh.g.ssum[3]);
        kl += pe * logf(pe / (pe + 1e-7f) + 1e-7f);
      }
      out[524288] = -0.01f * kl;              // mi_loss
    }
  }
}

// ---------------- K2/K3: conv3x3 via MFMA implicit GEMM ---------------------
// worklist-driven; block = 128 oc x 64 px (8x8); 4 waves x (32 oc x 64 px);
// A-frags global-streamed (3-deep), B-frags LDS double-buffered.
__global__ __launch_bounds__(256, 2) void conv_mfma(const float* __restrict__ wsf,
                                                    const ushort* __restrict__ pbuf,
                                                    ushort* __restrict__ buf1,
                                                    ushort* __restrict__ buf0,
                                                    const ushort* __restrict__ wt2,
                                                    int which,
                                                    const float* __restrict__ ball,
                                                    int gelu) {
  const int* wsi = (const int*)wsf;
  int bid = blockIdx.x;
  if (bid >= wsi[600]) return;
  int ent = wsi[640 + bid];
  int slot = ent & 7;
  int tile = (ent >> 4) & 63;
  int e    = (ent >> 12) & 15;
  int tp   = (ent >> 16) & 3;
  int b    = (ent >> 20) & 3;
  int S = (tp == 0) ? 32 : ((tp == 1) ? 64 : 16);
  int tpr = S >> 3;
  int tr = (tile / tpr) << 3;
  int tc = (tile % tpr) << 3;

  const ushort* in = which
      ? (buf1 + (size_t)slot * SLOT_ELEMS)
      : (pbuf + ((size_t)b * 5376 + (tp == 0 ? 0 : (tp == 1 ? 1024 : 5120))) * 128);
  ushort* outp = (which ? buf0 : buf1) + (size_t)slot * SLOT_ELEMS;

  __shared__ ushort sIn[100 * 136];       // [halo px][128 ch + 8 pad]
  int tid = threadIdx.x;

  for (int u = tid; u < 1600; u += 256) {
    int p = u >> 4, q = u & 15;
    int hr = p / 10, wc = p - hr * 10;
    int gh = tr + hr - 1, gw = tc + wc - 1;
    bf16x8 v = {0, 0, 0, 0, 0, 0, 0, 0};
    if (gh >= 0 && gh < S && gw >= 0 && gw < S)
      v = *(const bf16x8*)&in[(size_t)(gh * S + gw) * 128 + q * 8];
    *(bf16x8*)&sIn[p * 136 + q * 8] = v;
  }

  int wid = tid >> 6, lane = tid & 63;
  int ln = lane & 15, lg = lane >> 4;
  int ocw = wid << 5;
  const float* bias = ball + e * 128;

  // bias folded into acc init: row oc = m*16 + lg*4 + j
  f32x4 acc[2][4];
  #pragma unroll
  for (int m = 0; m < 2; ++m) {
    #pragma unroll
    for (int j = 0; j < 4; ++j) {
      float bv = bias[ocw + m * 16 + lg * 4 + j];
      #pragma unroll
      for (int n = 0; n < 4; ++n) acc[m][n][j] = bv;
    }
  }

  int pxb[4];
  #pragma unroll
  for (int n = 0; n < 4; ++n) {
    int px = n * 16 + ln;
    pxb[n] = (px >> 3) * 10 + (px & 7);
  }

  const ushort* wbase = wt2 + ((size_t)e * 2 + which) * 147456
                        + (size_t)(wid * 2) * 512 + lane * 8;

  bf16x8 abuf[3][2];
  #pragma unroll
  for (int i = 0; i < 2; ++i) {
    abuf[i][0] = *(const bf16x8*)&wbase[(size_t)i * 4096];
    abuf[i][1] = *(const bf16x8*)&wbase[(size_t)i * 4096 + 512];
  }

  __syncthreads();

  bf16x8 bcur[4], bnxt[4];
  #pragma unroll
  for (int n = 0; n < 4; ++n)                 // k=0: tap 0, icc 0
    bcur[n] = *(bf16x8*)&sIn[pxb[n] * 136 + lg * 8];

  #pragma unroll 6
  for (int kk = 0; kk < 36; ++kk) {           // k = tap*4 + icc
    if (kk + 2 < 36) {
      abuf[(kk + 2) % 3][0] = *(const bf16x8*)&wbase[(size_t)(kk + 2) * 4096];
      abuf[(kk + 2) % 3][1] = *(const bf16x8*)&wbase[(size_t)(kk + 2) * 4096 + 512];
    }
    int kn = kk + 1;
    if (kn < 36) {
      int tapn = kn >> 2, iccn = kn & 3;
      int offn = (tapn / 3) * 10 + (tapn % 3);
      #pragma unroll
      for (int n = 0; n < 4; ++n)
        bnxt[n] = *(bf16x8*)&sIn[(pxb[n] + offn) * 136 + iccn * 32 + lg * 8];
    }
    #pragma unroll
    for (int m = 0; m < 2; ++m)
      #pragma unroll
      for (int n = 0; n < 4; ++n)
        acc[m][n] = __builtin_amdgcn_mfma_f32_16x16x32_bf16(abuf[kk % 3][m], bcur[n],
                                                            acc[m][n], 0, 0, 0);
    #pragma unroll
    for (int n = 0; n < 4; ++n) bcur[n] = bnxt[n];
  }

  #pragma unroll
  for (int m = 0; m < 2; ++m) {
    int oc0 = ocw + m * 16 + lg * 4;
    #pragma unroll
    for (int n = 0; n < 4; ++n) {
      int px = n * 16 + ln;
      int gh = tr + (px >> 3), gw = tc + (px & 7);
      float v0 = acc[m][n][0];
      float v1 = acc[m][n][1];
      float v2 = acc[m][n][2];
      float v3 = acc[m][n][3];
      if (gelu) {
        v0 = gelu_fast(v0); v1 = gelu_fast(v1);
        v2 = gelu_fast(v2); v3 = gelu_fast(v3);
      }
      unsigned pk0 = (unsigned)f2bf(v0) | ((unsigned)f2bf(v1) << 16);
      unsigned pk1 = (unsigned)f2bf(v2) | ((unsigned)f2bf(v3) << 16);
      uint2 st; st.x = pk0; st.y = pk1;
      *(uint2*)&outp[(size_t)(gh * S + gw) * 128 + oc0] = st;
    }
  }
}

// ---------------- K4: combine — post * gate, NHWC bf16 -> NCHW f32 ----------
__global__ __launch_bounds__(256) void combine_kernel(const float* __restrict__ wsf,
                                                      const ushort* __restrict__ bufc,
                                                      float* __restrict__ out) {
  const int* wsi = (const int*)wsf;
  int chunk = blockIdx.x, b = blockIdx.y;   // 32 chunks x 32 px
  __shared__ float sO[32 * 129];
  int tid = threadIdx.x;

  #pragma unroll
  for (int i = 0; i < 2; ++i) {
    int u = i * 256 + tid;
    int pxl = u >> 4, q = u & 15;
    int px = chunk * 32 + pxl;
    int h = px >> 5, w = px & 31;
    float a8[8];
    #pragma unroll
    for (int j = 0; j < 8; ++j) a8[j] = 0.0f;

    for (int s = 0; s < 2; ++s) {
      int slot = 2 * b + s;
      int e = wsi[slot];
      float g = wsf[16 + slot];
      int tp = e % 3;
      const ushort* cin = bufc + (size_t)slot * SLOT_ELEMS;
      if (tp == 0) {
        bf16x8 v = *(const bf16x8*)&cin[(size_t)(h * 32 + w) * 128 + q * 8];
        #pragma unroll
        for (int j = 0; j < 8; ++j) a8[j] += g * bf2f((ushort)v[j]);
      } else if (tp == 1) {                 // maxpool from 64x64
        bf16x8 v00 = *(const bf16x8*)&cin[(size_t)((2*h) * 64 + 2*w) * 128 + q * 8];
        bf16x8 v01 = *(const bf16x8*)&cin[(size_t)((2*h) * 64 + 2*w + 1) * 128 + q * 8];
        bf16x8 v10 = *(const bf16x8*)&cin[(size_t)((2*h+1) * 64 + 2*w) * 128 + q * 8];
        bf16x8 v11 = *(const bf16x8*)&cin[(size_t)((2*h+1) * 64 + 2*w + 1) * 128 + q * 8];
        #pragma unroll
        for (int j = 0; j < 8; ++j) {
          float mv = fmaxf(fmaxf(bf2f((ushort)v00[j]), bf2f((ushort)v01[j])),
                           fmaxf(bf2f((ushort)v10[j]), bf2f((ushort)v11[j])));
          a8[j] += g * mv;
        }
      } else {                              // bilinear up from 16x16
        float sh2 = h * 0.5f - 0.25f, sw2 = w * 0.5f - 0.25f;
        float fh0 = floorf(sh2), fw0 = floorf(sw2);
        int h0 = (int)fh0, w0 = (int)fw0;
        float fh = sh2 - fh0, fw = sw2 - fw0;
        int h0c = h0 < 0 ? 0 : h0, h1c = (h0 + 1 > 15) ? 15 : h0 + 1;
        int w0c = w0 < 0 ? 0 : w0, w1c = (w0 + 1 > 15) ? 15 : w0 + 1;
        bf16x8 v00 = *(const bf16x8*)&cin[(size_t)(h0c * 16 + w0c) * 128 + q * 8];
        bf16x8 v01 = *(const bf16x8*)&cin[(size_t)(h0c * 16 + w1c) * 128 + q * 8];
        bf16x8 v10 = *(const bf16x8*)&cin[(size_t)(h1c * 16 + w0c) * 128 + q * 8];
        bf16x8 v11 = *(const bf16x8*)&cin[(size_t)(h1c * 16 + w1c) * 128 + q * 8];
        #pragma unroll
        for (int j = 0; j < 8; ++j) {
          float vv = (1.0f - fh) * ((1.0f - fw) * bf2f((ushort)v00[j]) + fw * bf2f((ushort)v01[j])) +
                     fh * ((1.0f - fw) * bf2f((ushort)v10[j]) + fw * bf2f((ushort)v11[j]));
          a8[j] += g * vv;
        }
      }
    }
    #pragma unroll
    for (int j = 0; j < 8; ++j) sO[pxl * 129 + q * 8 + j] = a8[j];
  }
  __syncthreads();
  float* ob = out + (size_t)b * 131072;
  #pragma unroll 4
  for (int i = 0; i < 16; ++i) {
    int u = i * 256 + tid;
    int c = u >> 5, pxl = u & 31;
    ob[(size_t)c * 1024 + chunk * 32 + pxl] = sO[pxl * 129 + c];
  }
}

// ---------------------------------------------------------------------------
extern "C" void kernel_launch(void* const* d_in, const int* in_sizes, int n_in,
                              void* d_out, int out_size, void* d_ws, size_t ws_size,
                              hipStream_t stream) {
  const float* x   = (const float*)d_in[0];
  const float* tf  = (const float*)d_in[1];
  const float* Wx  = (const float*)d_in[2];
  const float* Wt  = (const float*)d_in[3];
  const float* cw1 = (const float*)d_in[4];
  const float* cb1 = (const float*)d_in[5];
  const float* cw2 = (const float*)d_in[6];
  const float* cb2 = (const float*)d_in[7];
  float* out = (float*)d_out;

  float*  wsf  = (float*)d_ws;                    // 4096 f32
  ushort* wt2  = (ushort*)(wsf + 4096);           // 16*294912
  ushort* pbuf = wt2 + 16 * (size_t)WT_E;         // 4*5376*128
  ushort* buf1 = pbuf + 4 * 5376 * 128;           // 8*524288
  ushort* buf0 = buf1 + 8 * (size_t)SLOT_ELEMS;   // 8*524288

  // zero xp_done counter (ws is poisoned 0xAA before timing)
  hipMemsetAsync((char*)d_ws + 608 * sizeof(int), 0, 2 * sizeof(int), stream);

  hipLaunchKernelGGL(front_kernel, dim3(593), dim3(256), 0, stream,
                     x, tf, Wx, Wt, cw1, cw2, wsf, wt2, pbuf, out);
  hipLaunchKernelGGL(conv_mfma,    dim3(512), dim3(256), 0, stream,
                     wsf, pbuf, buf1, buf0, wt2, 0, cb1, 1);
  hipLaunchKernelGGL(conv_mfma,    dim3(512), dim3(256), 0, stream,
                     wsf, pbuf, buf1, buf0, wt2, 1, cb2, 0);
  hipLaunchKernelGGL(combine_kernel, dim3(32, 4), dim3(256), 0, stream,
                     wsf, buf0, out);
}

// Round 12
// 68.014 us; speedup vs baseline: 2.5280x; 1.0184x over previous
//
#include <hip/hip_runtime.h>
#include <math.h>

// ---------------------------------------------------------------------------
// MMoE feed-forward, round 11: conv latency attack.
//  - oc-split worklist: each tile -> 2 blocks (64oc x 64px), ~2x TLP
//  - depth-4 A-frag prefetch ring (static idx via unroll 4)
//   memset: zero wsi[608] (xp_done)
//   K1 frontG: xp(+release cnt) | wtrans | prep | block 592 = gate
//   K2 conv1 : worklist implicit-GEMM (bias + fast GELU)
//   K3 conv2 : worklist implicit-GEMM (bias)
//   K4 combine: post-transform * gate -> NCHW f32
// ---------------------------------------------------------------------------

typedef __attribute__((ext_vector_type(8))) short bf16x8;
typedef __attribute__((ext_vector_type(4))) float f32x4;

#define SLOT_ELEMS 524288
#define WT_E       294912            // per expert (both convs)

__device__ inline ushort f2bf(float f) {
  unsigned u = __float_as_uint(f);
  return (ushort)((u + 0x7FFFu + ((u >> 16) & 1u)) >> 16);
}
__device__ inline float bf2f(ushort h) {
  return __uint_as_float(((unsigned)h) << 16);
}
__device__ inline float gelu_fast(float v) {      // tanh-form GELU, err<~4e-4
  float v2 = v * v;
  float z2 = v * fmaf(0.0713548162726f, v2, 1.59576912161f);
  float ex = __expf(-z2);
  return __fdividef(v, 1.0f + ex);
}

// ---------------- K1: xp + wtrans + prep + gate(block 592) ------------------
__global__ __launch_bounds__(256) void front_kernel(const float* __restrict__ x,
                                                    const float* __restrict__ tf,
                                                    const float* __restrict__ Wx,
                                                    const float* __restrict__ Wt,
                                                    const float* __restrict__ cw1,
                                                    const float* __restrict__ cw2,
                                                    float* wsf,
                                                    ushort* __restrict__ wt2,
                                                    ushort* __restrict__ pbuf,
                                                    float* __restrict__ out) {
  int bid = blockIdx.x, tid = threadIdx.x;
  __shared__ union {
    float  red[4];                   // xp reduce
    ushort swT[1152 * 17];           // wtrans transpose: [r=ic*9+tap][oc] 39.2KB
    ushort sT[128 * 65];             // prep transpose
    struct {
      float part[4][64];
      float slog[64], sprob[64], ssum[4];
      int   se[16], snt[8];
    } g;                             // gate
  } sh;
  int* xp_done = (int*)wsf + 608;

  // ---- A: xp — (b,c) = bid (blocks 0..511) ----
  if (bid < 512) {
    const float4* p = (const float4*)(x + (size_t)bid * 1024);
    float4 v = p[tid];
    float s = v.x + v.y + v.z + v.w;
    #pragma unroll
    for (int off = 32; off > 0; off >>= 1) s += __shfl_down(s, off);
    if ((tid & 63) == 0) sh.red[tid >> 6] = s;
    __syncthreads();
    if (tid == 0) {
      wsf[64 + bid] = (sh.red[0] + sh.red[1] + sh.red[2] + sh.red[3]) *
                      (1.0f / 1024.0f);
      __hip_atomic_fetch_add(xp_done, 1, __ATOMIC_RELEASE,
                             __HIP_MEMORY_SCOPE_AGENT);
    }
    __syncthreads();                 // red dead before sh reuse
  }

  if (bid < 256) {
    // ---- B: wtrans block = (e, which, oc-block) ----
    int e = bid >> 4, which = (bid >> 3) & 1, blk = bid & 7;
    const float* src = (which ? cw2 : cw1) +
                       ((size_t)e * 128 + blk * 16) * 1152;
    #pragma unroll 24
    for (int i = 0; i < 72; ++i) {
      int idx = i * 256 + tid;                 // oc*1152 + r
      int oc = idx / 1152, r = idx - oc * 1152;
      sh.swT[r * 17 + oc] = f2bf(src[idx]);
    }
    __syncthreads();
    // emit MFMA-frag order: 36 chunks, 4 per iter; 16B/lane coalesced stores
    ushort* dst = wt2 + ((size_t)e * 2 + which) * 147456;
    int lane = tid & 63, cq = tid >> 6;
    int ol = lane & 15, h = lane >> 4;
    #pragma unroll
    for (int it = 0; it < 9; ++it) {
      int chunk = it * 4 + cq;                 // tap*4 + icc
      int tap = chunk >> 2, icc = chunk & 3;
      bf16x8 pkv;
      #pragma unroll
      for (int j = 0; j < 8; ++j) {
        int ic = icc * 32 + h * 8 + j;
        pkv[j] = (short)sh.swT[(ic * 9 + tap) * 17 + ol];
      }
      *(bf16x8*)&dst[((size_t)(chunk * 8 + blk)) * 512 + lane * 8] = pkv;
    }
  } else if (bid < 592) {
    // ---- C: prep — chunk pc = bid-256 of 336 (12 variants x 64px chunks) ----
    int pc = bid - 256;
    if (pc < 336) {
      int b = pc / 84, r = pc - (pc / 84) * 84;
      int tp, chunk, S, pp;
      if (r < 16)      { tp = 0; chunk = r;      S = 32; pp = 0; }
      else if (r < 80) { tp = 1; chunk = r - 16; S = 64; pp = 1024; }
      else             { tp = 2; chunk = r - 80; S = 16; pp = 5120; }
      const float* xb = x + (size_t)b * 131072;
      int pxl0 = tid & 63, c0 = tid >> 6;
      #pragma unroll 4
      for (int i = 0; i < 32; ++i) {
        int c = i * 4 + c0;
        int px = chunk * 64 + pxl0;
        float v;
        if (tp == 0) {
          v = xb[c * 1024 + px];
        } else if (tp == 1) {
          int h = px >> 6, w = px & 63;
          v = xb[c * 1024 + (h >> 1) * 32 + (w >> 1)];
        } else {
          int h = px >> 4, w = px & 15;
          const float* p = xb + c * 1024 + (h << 1) * 32 + (w << 1);
          v = fmaxf(fmaxf(p[0], p[1]), fmaxf(p[32], p[33]));
        }
        sh.sT[c * 65 + pxl0] = f2bf(v);
      }
      __syncthreads();
      ushort* ob = pbuf + ((size_t)b * 5376 + pp) * 128;
      #pragma unroll
      for (int i = 0; i < 4; ++i) {
        int u = i * 256 + tid;
        int pxl = u >> 4, q = u & 15;
        bf16x8 pk;
        #pragma unroll
        for (int j = 0; j < 8; ++j) pk[j] = (short)sh.sT[(q * 8 + j) * 65 + pxl];
        *(bf16x8*)&ob[(size_t)(chunk * 64 + pxl) * 128 + q * 8] = pk;
      }
    }
  } else {
    // ---- D: gate (block 592): RELAXED spin for 512 xp, one acquire fence ----
    if (tid == 0) {
      while (__hip_atomic_load(xp_done, __ATOMIC_RELAXED,
                               __HIP_MEMORY_SCOPE_AGENT) < 512)
        __builtin_amdgcn_s_sleep(2);
      __builtin_amdgcn_fence(__ATOMIC_ACQUIRE, "agent");
    }
    __syncthreads();

    int p = tid >> 6, be = tid & 63;
    int b = be >> 4, e = be & 15;
    const float* xp = wsf + 64;

    float acc = 0.0f;
    #pragma unroll 8
    for (int c = p * 32; c < p * 32 + 32; ++c)
      acc += xp[b * 128 + c] * Wx[c * 16 + e];
    {
      const float4* tf4 = (const float4*)(tf + b * 512 + p * 128);
      #pragma unroll 8
      for (int d4 = 0; d4 < 32; ++d4) {
        float4 t4 = tf4[d4];
        int d = p * 128 + d4 * 4;
        acc += t4.x * Wt[(d + 0) * 16 + e];
        acc += t4.y * Wt[(d + 1) * 16 + e];
        acc += t4.z * Wt[(d + 2) * 16 + e];
        acc += t4.w * Wt[(d + 3) * 16 + e];
      }
    }
    sh.g.part[p][be] = acc;
    __syncthreads();

    if (tid < 64) sh.g.slog[be] = sh.g.part[0][be] + sh.g.part[1][be] +
                                  sh.g.part[2][be] + sh.g.part[3][be];
    __syncthreads();
    if (tid < 64) {
      float m = sh.g.slog[b * 16];
      for (int j = 1; j < 16; ++j) m = fmaxf(m, sh.g.slog[b * 16 + j]);
      sh.g.sprob[be] = expf(sh.g.slog[be] - m);
    }
    __syncthreads();
    if (tid < 4) {                            // tid = b
      float s = 0.0f;
      for (int j = 0; j < 16; ++j) s += sh.g.sprob[tid * 16 + j];
      sh.g.ssum[tid] = s;
      int i1 = 0; float v1 = -1.0f;
      for (int j = 0; j < 16; ++j) {
        float v = sh.g.sprob[tid * 16 + j];
        if (v > v1) { v1 = v; i1 = j; }
      }
      int i2 = -1; float v2 = -1.0f;
      for (int j = 0; j < 16; ++j) {
        if (j == i1) continue;
        float v = sh.g.sprob[tid * 16 + j];
        if (v > v2) { v2 = v; i2 = j; }
      }
      float inv = 1.0f / (v1 + v2);           // softmax denom cancels
      int* wsi = (int*)wsf;
      wsi[2 * tid]     = i1;  wsi[2 * tid + 1]     = i2;
      wsi[8 + 2 * tid] = tid; wsi[8 + 2 * tid + 1] = tid;
      wsf[16 + 2 * tid]     = v1 * inv;
      wsf[16 + 2 * tid + 1] = v2 * inv;
      sh.g.se[2 * tid] = i1; sh.g.se[2 * tid + 1] = i2;
    }
    __syncthreads();
    if (tid < 8) {
      int ee = sh.g.se[tid];
      int tp = ee % 3;
      sh.g.snt[tid] = (tp == 0) ? 16 : ((tp == 1) ? 64 : 4);
    }
    __syncthreads();
    if (tid < 8) {            // planner: 2 entries per tile (oc halves)
      int pre = 0;
      #pragma unroll
      for (int s = 0; s < 8; ++s) pre += (s < tid) ? sh.g.snt[s] : 0;
      int ee = sh.g.se[tid];
      int tp = ee % 3;
      int nt = sh.g.snt[tid];
      int bb = tid >> 1;
      int ent_base = tid | (ee << 12) | (tp << 16) | (bb << 20);
      int* wl = (int*)wsf + 640;
      for (int t = 0; t < nt; ++t) {
        int eb = ent_base | (t << 4);
        wl[(pre + t) * 2]     = eb;
        wl[(pre + t) * 2 + 1] = eb | (1 << 22);
      }
      if (tid == 7) ((int*)wsf)[600] = (pre + nt) * 2;
    }
    if (tid == 32) {
      float kl = 0.0f;
      for (int j = 0; j < 16; ++j) {
        float pe = 0.25f * (sh.g.sprob[j] / sh.g.ssum[0] +
                            sh.g.sprob[16 + j] / sh.g.ssum[1] +
                            sh.g.sprob[32 + j] / sh.g.ssum[2] +
                            sh.g.sprob[48 + j] / sh.g.ssum[3]);
        kl += pe * logf(pe / (pe + 1e-7f) + 1e-7f);
      }
      out[524288] = -0.01f * kl;              // mi_loss
    }
  }
}

// ---------------- K2/K3: conv3x3 via MFMA implicit GEMM ---------------------
// worklist-driven; block = 64 oc x 64 px (oc-split); 4 waves x (16 oc x 64 px)
// A-frags global-streamed depth-4 ring; B-frags LDS double-buffered.
__global__ __launch_bounds__(256, 4) void conv_mfma(const float* __restrict__ wsf,
                                                    const ushort* __restrict__ pbuf,
                                                    ushort* __restrict__ buf1,
                                                    ushort* __restrict__ buf0,
                                                    const ushort* __restrict__ wt2,
                                                    int which,
                                                    const float* __restrict__ ball,
                                                    int gelu) {
  const int* wsi = (const int*)wsf;
  int bid = blockIdx.x;
  if (bid >= wsi[600]) return;
  int ent = wsi[640 + bid];
  int slot = ent & 7;
  int tile = (ent >> 4) & 63;
  int e    = (ent >> 12) & 15;
  int tp   = (ent >> 16) & 3;
  int b    = (ent >> 20) & 3;
  int half = (ent >> 22) & 1;
  int S = (tp == 0) ? 32 : ((tp == 1) ? 64 : 16);
  int tpr = S >> 3;
  int tr = (tile / tpr) << 3;
  int tc = (tile % tpr) << 3;

  const ushort* in = which
      ? (buf1 + (size_t)slot * SLOT_ELEMS)
      : (pbuf + ((size_t)b * 5376 + (tp == 0 ? 0 : (tp == 1 ? 1024 : 5120))) * 128);
  ushort* outp = (which ? buf0 : buf1) + (size_t)slot * SLOT_ELEMS;

  __shared__ ushort sIn[100 * 136];       // [halo px][128 ch + 8 pad]
  int tid = threadIdx.x;

  for (int u = tid; u < 1600; u += 256) {
    int p = u >> 4, q = u & 15;
    int hr = p / 10, wc = p - hr * 10;
    int gh = tr + hr - 1, gw = tc + wc - 1;
    bf16x8 v = {0, 0, 0, 0, 0, 0, 0, 0};
    if (gh >= 0 && gh < S && gw >= 0 && gw < S)
      v = *(const bf16x8*)&in[(size_t)(gh * S + gw) * 128 + q * 8];
    *(bf16x8*)&sIn[p * 136 + q * 8] = v;
  }

  int wid = tid >> 6, lane = tid & 63;
  int ln = lane & 15, lg = lane >> 4;
  int blk16 = half * 4 + wid;              // oc16-chunk this wave owns
  int ocw = blk16 << 4;
  const float* bias = ball + e * 128;

  // bias folded into acc init: row oc = ocw + lg*4 + j
  f32x4 acc[4];
  #pragma unroll
  for (int j = 0; j < 4; ++j) {
    float bv = bias[ocw + lg * 4 + j];
    #pragma unroll
    for (int n = 0; n < 4; ++n) acc[n][j] = bv;
  }

  int pxb[4];
  #pragma unroll
  for (int n = 0; n < 4; ++n) {
    int px = n * 16 + ln;
    pxb[n] = (px >> 3) * 10 + (px & 7);
  }

  const ushort* wbase = wt2 + ((size_t)e * 2 + which) * 147456
                        + (size_t)blk16 * 512 + lane * 8;

  bf16x8 abuf[4];
  #pragma unroll
  for (int i = 0; i < 3; ++i)
    abuf[i] = *(const bf16x8*)&wbase[(size_t)i * 4096];

  __syncthreads();

  bf16x8 bcur[4], bnxt[4];
  #pragma unroll
  for (int n = 0; n < 4; ++n)                 // k=0: tap 0, icc 0
    bcur[n] = *(bf16x8*)&sIn[pxb[n] * 136 + lg * 8];

  #pragma unroll 4
  for (int kk = 0; kk < 36; ++kk) {           // k = tap*4 + icc
    if (kk + 3 < 36)
      abuf[(kk + 3) & 3] = *(const bf16x8*)&wbase[(size_t)(kk + 3) * 4096];
    int kn = kk + 1;
    if (kn < 36) {
      int tapn = kn >> 2, iccn = kn & 3;
      int offn = (tapn / 3) * 10 + (tapn % 3);
      #pragma unroll
      for (int n = 0; n < 4; ++n)
        bnxt[n] = *(bf16x8*)&sIn[(pxb[n] + offn) * 136 + iccn * 32 + lg * 8];
    }
    #pragma unroll
    for (int n = 0; n < 4; ++n)
      acc[n] = __builtin_amdgcn_mfma_f32_16x16x32_bf16(abuf[kk & 3], bcur[n],
                                                       acc[n], 0, 0, 0);
    #pragma unroll
    for (int n = 0; n < 4; ++n) bcur[n] = bnxt[n];
  }

  int oc0 = ocw + lg * 4;
  #pragma unroll
  for (int n = 0; n < 4; ++n) {
    int px = n * 16 + ln;
    int gh = tr + (px >> 3), gw = tc + (px & 7);
    float v0 = acc[n][0];
    float v1 = acc[n][1];
    float v2 = acc[n][2];
    float v3 = acc[n][3];
    if (gelu) {
      v0 = gelu_fast(v0); v1 = gelu_fast(v1);
      v2 = gelu_fast(v2); v3 = gelu_fast(v3);
    }
    unsigned pk0 = (unsigned)f2bf(v0) | ((unsigned)f2bf(v1) << 16);
    unsigned pk1 = (unsigned)f2bf(v2) | ((unsigned)f2bf(v3) << 16);
    uint2 st; st.x = pk0; st.y = pk1;
    *(uint2*)&outp[(size_t)(gh * S + gw) * 128 + oc0] = st;
  }
}

// ---------------- K4: combine — post * gate, NHWC bf16 -> NCHW f32 ----------
__global__ __launch_bounds__(256) void combine_kernel(const float* __restrict__ wsf,
                                                      const ushort* __restrict__ bufc,
                                                      float* __restrict__ out) {
  const int* wsi = (const int*)wsf;
  int chunk = blockIdx.x, b = blockIdx.y;   // 32 chunks x 32 px
  __shared__ float sO[32 * 129];
  int tid = threadIdx.x;

  #pragma unroll
  for (int i = 0; i < 2; ++i) {
    int u = i * 256 + tid;
    int pxl = u >> 4, q = u & 15;
    int px = chunk * 32 + pxl;
    int h = px >> 5, w = px & 31;
    float a8[8];
    #pragma unroll
    for (int j = 0; j < 8; ++j) a8[j] = 0.0f;

    for (int s = 0; s < 2; ++s) {
      int slot = 2 * b + s;
      int e = wsi[slot];
      float g = wsf[16 + slot];
      int tp = e % 3;
      const ushort* cin = bufc + (size_t)slot * SLOT_ELEMS;
      if (tp == 0) {
        bf16x8 v = *(const bf16x8*)&cin[(size_t)(h * 32 + w) * 128 + q * 8];
        #pragma unroll
        for (int j = 0; j < 8; ++j) a8[j] += g * bf2f((ushort)v[j]);
      } else if (tp == 1) {                 // maxpool from 64x64
        bf16x8 v00 = *(const bf16x8*)&cin[(size_t)((2*h) * 64 + 2*w) * 128 + q * 8];
        bf16x8 v01 = *(const bf16x8*)&cin[(size_t)((2*h) * 64 + 2*w + 1) * 128 + q * 8];
        bf16x8 v10 = *(const bf16x8*)&cin[(size_t)((2*h+1) * 64 + 2*w) * 128 + q * 8];
        bf16x8 v11 = *(const bf16x8*)&cin[(size_t)((2*h+1) * 64 + 2*w + 1) * 128 + q * 8];
        #pragma unroll
        for (int j = 0; j < 8; ++j) {
          float mv = fmaxf(fmaxf(bf2f((ushort)v00[j]), bf2f((ushort)v01[j])),
                           fmaxf(bf2f((ushort)v10[j]), bf2f((ushort)v11[j])));
          a8[j] += g * mv;
        }
      } else {                              // bilinear up from 16x16
        float sh2 = h * 0.5f - 0.25f, sw2 = w * 0.5f - 0.25f;
        float fh0 = floorf(sh2), fw0 = floorf(sw2);
        int h0 = (int)fh0, w0 = (int)fw0;
        float fh = sh2 - fh0, fw = sw2 - fw0;
        int h0c = h0 < 0 ? 0 : h0, h1c = (h0 + 1 > 15) ? 15 : h0 + 1;
        int w0c = w0 < 0 ? 0 : w0, w1c = (w0 + 1 > 15) ? 15 : w0 + 1;
        bf16x8 v00 = *(const bf16x8*)&cin[(size_t)(h0c * 16 + w0c) * 128 + q * 8];
        bf16x8 v01 = *(const bf16x8*)&cin[(size_t)(h0c * 16 + w1c) * 128 + q * 8];
        bf16x8 v10 = *(const bf16x8*)&cin[(size_t)(h1c * 16 + w0c) * 128 + q * 8];
        bf16x8 v11 = *(const bf16x8*)&cin[(size_t)(h1c * 16 + w1c) * 128 + q * 8];
        #pragma unroll
        for (int j = 0; j < 8; ++j) {
          float vv = (1.0f - fh) * ((1.0f - fw) * bf2f((ushort)v00[j]) + fw * bf2f((ushort)v01[j])) +
                     fh * ((1.0f - fw) * bf2f((ushort)v10[j]) + fw * bf2f((ushort)v11[j]));
          a8[j] += g * vv;
        }
      }
    }
    #pragma unroll
    for (int j = 0; j < 8; ++j) sO[pxl * 129 + q * 8 + j] = a8[j];
  }
  __syncthreads();
  float* ob = out + (size_t)b * 131072;
  #pragma unroll 4
  for (int i = 0; i < 16; ++i) {
    int u = i * 256 + tid;
    int c = u >> 5, pxl = u & 31;
    ob[(size_t)c * 1024 + chunk * 32 + pxl] = sO[pxl * 129 + c];
  }
}

// ---------------------------------------------------------------------------
extern "C" void kernel_launch(void* const* d_in, const int* in_sizes, int n_in,
                              void* d_out, int out_size, void* d_ws, size_t ws_size,
                              hipStream_t stream) {
  const float* x   = (const float*)d_in[0];
  const float* tf  = (const float*)d_in[1];
  const float* Wx  = (const float*)d_in[2];
  const float* Wt  = (const float*)d_in[3];
  const float* cw1 = (const float*)d_in[4];
  const float* cb1 = (const float*)d_in[5];
  const float* cw2 = (const float*)d_in[6];
  const float* cb2 = (const float*)d_in[7];
  float* out = (float*)d_out;

  float*  wsf  = (float*)d_ws;                    // 4096 f32
  ushort* wt2  = (ushort*)(wsf + 4096);           // 16*294912
  ushort* pbuf = wt2 + 16 * (size_t)WT_E;         // 4*5376*128
  ushort* buf1 = pbuf + 4 * 5376 * 128;           // 8*524288
  ushort* buf0 = buf1 + 8 * (size_t)SLOT_ELEMS;   // 8*524288

  // zero xp_done counter (ws is poisoned 0xAA before timing)
  hipMemsetAsync((char*)d_ws + 608 * sizeof(int), 0, 2 * sizeof(int), stream);

  hipLaunchKernelGGL(front_kernel, dim3(593), dim3(256), 0, stream,
                     x, tf, Wx, Wt, cw1, cw2, wsf, wt2, pbuf, out);
  hipLaunchKernelGGL(conv_mfma,    dim3(1024), dim3(256), 0, stream,
                     wsf, pbuf, buf1, buf0, wt2, 0, cb1, 1);
  hipLaunchKernelGGL(conv_mfma,    dim3(1024), dim3(256), 0, stream,
                     wsf, pbuf, buf1, buf0, wt2, 1, cb2, 0);
  hipLaunchKernelGGL(combine_kernel, dim3(32, 4), dim3(256), 0, stream,
                     wsf, buf0, out);
}